// Round 13
// baseline (60.371 us; speedup 1.0000x reference)
//
#include <hip/hip_runtime.h>
#include <hip/hip_bf16.h>
#include <math.h>

// y[n,o] = min_i (x[n,i] + w[o,i]) + bias[o]
// x: (32768,128) f32, w: (128,128) f32, bias: (128,) f32, out: (32768,128) f32
//
// Zero-LDS main loop. Lane owns one x ROW (64 h2 VGPRs, loaded once, static
// indices). Column loop is wave-uniform -> w streams through the SCALAR pipe
// (s_load_dwordx4) and feeds v_pk_add_f16 as the SGPR operand (VOP3P allows
// 1 SGPR src). Main loop pipes: VALU + SALU only -- no LDS return-BW cap
// (the ~12cyc/KB ds_read ceiling that explains rounds 2-12's 25-29us floor).
// w is pre-converted f32->f16 into d_ws by a tiny kernel (no scalar cvt op).

typedef __fp16 h2 __attribute__((ext_vector_type(2)));

constexpr int K = 128;

__global__ void cvt_w_kernel(const float* __restrict__ w, __fp16* __restrict__ wh) {
    int i = blockIdx.x * 256 + threadIdx.x;       // 4096 threads, 4 elems each
    float4 v = *(const float4*)(w + (size_t)i * 4);
    h2 a = __builtin_amdgcn_cvt_pkrtz(v.x, v.y);
    h2 b = __builtin_amdgcn_cvt_pkrtz(v.z, v.w);
    *(h2*)(wh + (size_t)i * 4)     = a;
    *(h2*)(wh + (size_t)i * 4 + 2) = b;
}

__global__ __launch_bounds__(256, 2)
void minplus_kernel(const float* __restrict__ x,
                    const __fp16* __restrict__ wh,
                    const float* __restrict__ bias,
                    float* __restrict__ out,
                    int nrows)
{
    const int t   = blockIdx.x * 256 + threadIdx.x;
    const int row = t & (nrows - 1);             // consecutive lanes -> consecutive rows
    const int cg  = t / nrows;                   // col-group 0..3 (32 cols each)
    const int colbase = cg * 32;

    // ---- my x row: 32 float4 loads -> 64 h2 regs (all static indices) ----
    const float4* xrow = (const float4*)(x + (size_t)row * K);
    h2 xr[64];
    #pragma unroll
    for (int q = 0; q < 32; ++q) {
        float4 v = xrow[q];
        xr[2 * q + 0] = __builtin_amdgcn_cvt_pkrtz(v.x, v.y);
        xr[2 * q + 1] = __builtin_amdgcn_cvt_pkrtz(v.z, v.w);
    }

    h2 hbig;
    hbig.x = (__fp16)65504.0f;
    hbig.y = (__fp16)65504.0f;

    float* orow = out + (size_t)row * K;

    #pragma unroll 2
    for (int o = 0; o < 32; ++o) {
        const int col = colbase + o;
        const uint4* wr = (const uint4*)(wh + (size_t)col * K);  // wave-uniform -> s_load
        h2 a0 = hbig, a1 = hbig, a2 = hbig, a3 = hbig;           // 4 ILP chains

        // 32 dwords = 64 h2 per k-half; math: v_pk_add_f16 (s-src) + v_pk_min_f16
#define DO4(U, G)                                                             \
        {                                                                     \
            h2 s0 = xr[(G) + 0] + __builtin_bit_cast(h2, (U).x);              \
            a0 = __builtin_elementwise_min(a0, s0);                           \
            h2 s1 = xr[(G) + 1] + __builtin_bit_cast(h2, (U).y);              \
            a1 = __builtin_elementwise_min(a1, s1);                           \
            h2 s2 = xr[(G) + 2] + __builtin_bit_cast(h2, (U).z);              \
            a2 = __builtin_elementwise_min(a2, s2);                           \
            h2 s3 = xr[(G) + 3] + __builtin_bit_cast(h2, (U).w);              \
            a3 = __builtin_elementwise_min(a3, s3);                           \
        }
        #pragma unroll
        for (int h = 0; h < 2; ++h) {            // two 64-elem halves of the w row
            uint4 u0 = wr[h * 8 + 0];
            uint4 u1 = wr[h * 8 + 1];
            uint4 u2 = wr[h * 8 + 2];
            uint4 u3 = wr[h * 8 + 3];
            uint4 u4 = wr[h * 8 + 4];
            uint4 u5 = wr[h * 8 + 5];
            uint4 u6 = wr[h * 8 + 6];
            uint4 u7 = wr[h * 8 + 7];
            DO4(u0, h * 32 + 0)  DO4(u1, h * 32 + 4)
            DO4(u2, h * 32 + 8)  DO4(u3, h * 32 + 12)
            DO4(u4, h * 32 + 16) DO4(u5, h * 32 + 20)
            DO4(u6, h * 32 + 24) DO4(u7, h * 32 + 28)
        }
#undef DO4

        h2 m = __builtin_elementwise_min(__builtin_elementwise_min(a0, a1),
                                         __builtin_elementwise_min(a2, a3));
        float r = fminf((float)m.x, (float)m.y) + bias[col];   // bias: s_load
        orow[col] = r;                                          // L2 merges dwords
    }
}

extern "C" void kernel_launch(void* const* d_in, const int* in_sizes, int n_in,
                              void* d_out, int out_size, void* d_ws, size_t ws_size,
                              hipStream_t stream) {
    const float* x    = (const float*)d_in[0];
    const float* w    = (const float*)d_in[1];
    const float* bias = (const float*)d_in[2];
    float* out = (float*)d_out;
    __fp16* wh = (__fp16*)d_ws;                  // 32 KB of workspace for f16 w

    cvt_w_kernel<<<16, 256, 0, stream>>>(w, wh);

    int nrows   = in_sizes[0] / K;               // 32768
    int threads = nrows * 4;                     // 4 col-groups per row
    minplus_kernel<<<threads / 256, 256, 0, stream>>>(x, wh, bias, out, nrows);
}

// Round 14
// 43.263 us; speedup vs baseline: 1.3955x; 1.3955x over previous
//
#include <hip/hip_runtime.h>
#include <hip/hip_bf16.h>
#include <math.h>

// y[n,o] = min_i (x[n,i] + w[o,i]) + bias[o]
// x: (32768,128) f32, w: (128,128) f32, bias: (128,) f32, out: (32768,128) f32
//
// BM=64 x BN=128 (no col split -> x staged/fetched ONCE). x-tile in LDS (f16,
// pad-68 rows, broadcast-read). w as f16 in d_ws (32 KB = L1-resident), read
// per-lane from global on the VMEM pipe inside the loop (8 named row pointers
// + imm offsets; in-loop loads have no residency/remat hazard). Thread tile
// 4 rows x 8 cols: per kc = 4 LDS reads + 8 L1 loads + 256 pk-VALU.
// Pipes: VALU 6.8us (cap), LDS ~2.6us, VMEM ~2.6-5us, all parallel.

typedef __fp16 h2 __attribute__((ext_vector_type(2)));
typedef __fp16 h4 __attribute__((ext_vector_type(4)));
typedef __fp16 h8 __attribute__((ext_vector_type(8)));

constexpr int K     = 128;
constexpr int BM    = 64;
constexpr int LDRH2 = 68;        // x row stride in h2 units (272 B, 16B-aligned)

__global__ void cvt_w_kernel(const float* __restrict__ w, __fp16* __restrict__ wh) {
    int i = blockIdx.x * 256 + threadIdx.x;       // 4096 threads, 4 elems each
    float4 v = *(const float4*)(w + (size_t)i * 4);
    h2 a = __builtin_amdgcn_cvt_pkrtz(v.x, v.y);
    h2 b = __builtin_amdgcn_cvt_pkrtz(v.z, v.w);
    *(h4*)(wh + (size_t)i * 4) = __builtin_shufflevector(a, b, 0, 1, 2, 3);
}

__global__ __launch_bounds__(256, 2)
void minplus_kernel(const float* __restrict__ x,
                    const __fp16* __restrict__ wh,
                    const float* __restrict__ bias,
                    float* __restrict__ out)
{
    __shared__ h2 xs[BM * LDRH2];            // 17,408 B

    const int tid = threadIdx.x;
    const float* xsrc = x + (size_t)blockIdx.x * BM * K;

    // ---- stage x tile (64x128) once, f32 -> f16, coalesced ----
    #pragma unroll
    for (int p = 0; p < 8; ++p) {
        int c   = p * 256 + tid;             // float4-chunk id, 0..2047
        int row = c >> 5;                    // 0..63
        int q   = c & 31;
        float4 v = *(const float4*)(xsrc + row * K + q * 4);
        h2 a = __builtin_amdgcn_cvt_pkrtz(v.x, v.y);
        h2 b = __builtin_amdgcn_cvt_pkrtz(v.z, v.w);
        *(h4*)(xs + row * LDRH2 + q * 2) = __builtin_shufflevector(a, b, 0, 1, 2, 3);
    }
    __syncthreads();                         // the ONLY barrier

    const int ty = tid >> 4;                 // 0..15 : rows ty + 16m, m=0..3
    const int tx = tid & 15;                 // 0..15 : cols tx + 16n, n=0..7
    const h2* xbp = xs + ty * LDRH2;         // one vaddr, imm offsets <= 13,296 B

    // 8 named w row pointers (f16 rows, 256 B each; L1-resident after 1st gen)
    const __fp16* wp0 = wh + (size_t)(tx +   0) * K;
    const __fp16* wp1 = wh + (size_t)(tx +  16) * K;
    const __fp16* wp2 = wh + (size_t)(tx +  32) * K;
    const __fp16* wp3 = wh + (size_t)(tx +  48) * K;
    const __fp16* wp4 = wh + (size_t)(tx +  64) * K;
    const __fp16* wp5 = wh + (size_t)(tx +  80) * K;
    const __fp16* wp6 = wh + (size_t)(tx +  96) * K;
    const __fp16* wp7 = wh + (size_t)(tx + 112) * K;

    h2 hbig;
    hbig.x = (__fp16)65504.0f;
    hbig.y = (__fp16)65504.0f;
    h2 acc[4][8];
    #pragma unroll
    for (int m = 0; m < 4; ++m)
        #pragma unroll
        for (int n = 0; n < 8; ++n)
            acc[m][n] = hbig;

    // ---- 16 chunks of 8 k-elems: 4 ds_read_b128 + 8 global_load_dwordx4
    //      + 256 pk-VALU each ----
    #pragma unroll 2
    for (int kc = 0; kc < 16; ++kc) {
        h8 xv0 = *(const h8*)(xbp + 0 * 16 * LDRH2 + kc * 4);
        h8 xv1 = *(const h8*)(xbp + 1 * 16 * LDRH2 + kc * 4);
        h8 xv2 = *(const h8*)(xbp + 2 * 16 * LDRH2 + kc * 4);
        h8 xv3 = *(const h8*)(xbp + 3 * 16 * LDRH2 + kc * 4);
        h8 wv0 = *(const h8*)(wp0 + kc * 8);
        h8 wv1 = *(const h8*)(wp1 + kc * 8);
        h8 wv2 = *(const h8*)(wp2 + kc * 8);
        h8 wv3 = *(const h8*)(wp3 + kc * 8);
        h8 wv4 = *(const h8*)(wp4 + kc * 8);
        h8 wv5 = *(const h8*)(wp5 + kc * 8);
        h8 wv6 = *(const h8*)(wp6 + kc * 8);
        h8 wv7 = *(const h8*)(wp7 + kc * 8);

#define UPD(m, n, XV, WV)                                                     \
        {                                                                     \
            h8 t  = XV + WV;                 /* 4x v_pk_add_f16 */            \
            h2 t0 = __builtin_shufflevector(t, t, 0, 1);                      \
            h2 t1 = __builtin_shufflevector(t, t, 2, 3);                      \
            h2 t2 = __builtin_shufflevector(t, t, 4, 5);                      \
            h2 t3 = __builtin_shufflevector(t, t, 6, 7);                      \
            h2 u  = __builtin_elementwise_min(t0, t1);                        \
            h2 v  = __builtin_elementwise_min(t2, t3);                        \
            h2 uv = __builtin_elementwise_min(u, v);                          \
            acc[m][n] = __builtin_elementwise_min(acc[m][n], uv);             \
        }
#define ROW(m, XV)                                                            \
        UPD(m, 0, XV, wv0) UPD(m, 1, XV, wv1) UPD(m, 2, XV, wv2)              \
        UPD(m, 3, XV, wv3) UPD(m, 4, XV, wv4) UPD(m, 5, XV, wv5)              \
        UPD(m, 6, XV, wv6) UPD(m, 7, XV, wv7)
        ROW(0, xv0) ROW(1, xv1) ROW(2, xv2) ROW(3, xv3)
#undef ROW
#undef UPD
    }

    // ---- epilogue: f16 pair-reduce -> f32, + bias, store ----
    const int rowbase = blockIdx.x * BM + ty;
    #pragma unroll
    for (int n = 0; n < 8; ++n) {
        float b = bias[tx + 16 * n];
        #pragma unroll
        for (int m = 0; m < 4; ++m) {
            h2 a = acc[m][n];
            out[(size_t)(rowbase + 16 * m) * 128 + tx + 16 * n] =
                fminf((float)a.x, (float)a.y) + b;
        }
    }
}

extern "C" void kernel_launch(void* const* d_in, const int* in_sizes, int n_in,
                              void* d_out, int out_size, void* d_ws, size_t ws_size,
                              hipStream_t stream) {
    const float* x    = (const float*)d_in[0];
    const float* w    = (const float*)d_in[1];
    const float* bias = (const float*)d_in[2];
    float* out = (float*)d_out;
    __fp16* wh = (__fp16*)d_ws;              // 32 KB f16 copy of w

    cvt_w_kernel<<<16, 256, 0, stream>>>(w, wh);

    int nrows  = in_sizes[0] / K;            // 32768
    int blocks = nrows / BM;                 // 512
    minplus_kernel<<<blocks, 256, 0, stream>>>(x, wh, bias, out);
}